// Round 15
// baseline (5723.661 us; speedup 1.0000x reference)
//
#include <hip/hip_runtime.h>

#define TT 512
#define BB 64
#define HH 1024
#define EE 512
#define VV 50000
#define BBHH (BB*HH)
#define BPL 128
#define NBLK 256

typedef __attribute__((ext_vector_type(8))) short bf16x8;
typedef __attribute__((ext_vector_type(4))) float f32x4;
typedef unsigned short us;

#define MFMA(a,b,c) __builtin_amdgcn_mfma_f32_16x16x32_bf16((a),(b),(c),0,0,0)
#define LDG(p) __hip_atomic_load((p), __ATOMIC_RELAXED, __HIP_MEMORY_SCOPE_AGENT)

__device__ inline us f2b(float f){
  unsigned u; __builtin_memcpy(&u, &f, 4);
  return (us)((u + 0x7FFFu + ((u >> 16) & 1u)) >> 16);
}
__device__ inline float sigmoidf_(float x){ return 1.0f / (1.0f + __expf(-x)); }
__device__ inline float tanhf_(float x){ float e = __expf(2.0f * x); return 1.0f - 2.0f / (e + 1.0f); }

__device__ inline bf16x8 pack8(float4 a, float4 b){
  bf16x8 r;
  r[0]=(short)f2b(a.x); r[1]=(short)f2b(a.y); r[2]=(short)f2b(a.z); r[3]=(short)f2b(a.w);
  r[4]=(short)f2b(b.x); r[5]=(short)f2b(b.y); r[6]=(short)f2b(b.z); r[7]=(short)f2b(b.w);
  return r;
}

// ---------------- cast fp32 -> bf16 ----------------
__global__ void cast_f2b(const float* __restrict__ src, us* __restrict__ dst, long n){
  long i = ((long)blockIdx.x * blockDim.x + threadIdx.x) * 4;
  long stride = (long)gridDim.x * blockDim.x * 4;
  for (; i + 3 < n; i += stride){
    float4 v = *reinterpret_cast<const float4*>(src + i);
    ushort4 r; r.x=f2b(v.x); r.y=f2b(v.y); r.z=f2b(v.z); r.w=f2b(v.w);
    *reinterpret_cast<ushort4*>(dst + i) = r;
  }
}

// ---------------- init: h0 fp32 [2,B,H] -> compact [j>>3][b][j&7] bf16 ----------------
__global__ void init_h(const float* __restrict__ h0,
                       us* __restrict__ h0ic, us* __restrict__ h1ic){
  int i = blockIdx.x * blockDim.x + threadIdx.x;   // b*HH + j
  int b = i >> 10, j = i & (HH - 1);
  int d = (((j >> 3) * BB) + b) * 8 + (j & 7);
  h0ic[d] = f2b(h0[i]);
  h1ic[d] = f2b(h0[BBHH + i]);
}

// ---------------- per-wave producer-window wait (monolithic, for rare paths) ----------------
__device__ __forceinline__ void wait_win(const unsigned* __restrict__ f, int base,
                                         unsigned e, int lane){
  const unsigned* p = f + base + (lane & 31);
  unsigned a = LDG(p);
  while (!__all((int)(a >= e))){
    __builtin_amdgcn_s_sleep(8);
    a = LDG(p);
  }
}

// publish: drain this block's sc1 stores, block-barrier, one flag store
__device__ __forceinline__ void publish(unsigned* __restrict__ f, int bid_l, unsigned e){
  asm volatile("s_waitcnt vmcnt(0)" ::: "memory");
  __syncthreads();
  if (threadIdx.x == 0)
    __hip_atomic_store(f + bid_l, e, __ATOMIC_RELAXED, __HIP_MEMORY_SCOPE_AGENT);
}

// chunk kk ready-mask: lanes holding flags for producers wid*32+kk*4+{0..3}
// = lanes with (lane&31)>>2 == kk (present in both wave halves)
__device__ __forceinline__ unsigned long long cmask(int kk){
  return (0xFULL << (kk * 4)) | (0xFULL << (kk * 4 + 32));
}

// Lane mapping (per m in 0..1): A-row l16 -> (g=l16&3, u=2*(l16>>2)+m);
// D row hi*4+i -> unit j0+2*hi+m, gate i; lane owns batch bown=wid*16+l16.
#define LIDX(m, s) ((((m) * 16 + (s)) * 64 + lane) * 4)

// consumer base offset into compact h: k = wid*256 + kk*32 + kq -> kblk = wid*32+kk*4+hi
#define CBASE ((wid * 32 + hi) * (BB * 8) + l16 * 8)

__device__ void run_l0(
    int bid_l, int lane, int wid, int l16, int hi, int kq,
    const int* __restrict__ inputs, const float* __restrict__ c0,
    const us* __restrict__ emb_bf,
    const float* __restrict__ Wih0, const float* __restrict__ Whh0,
    const us* __restrict__ h0ic,
    us* __restrict__ hist0,
    float* __restrict__ hn, float* __restrict__ cn,
    unsigned* __restrict__ flags0, float* lds)
{
  const int j0 = bid_l * 8;
  const int bown = wid * 16 + l16;
  const int cbase = CBASE;
  const int wbase = wid * 32;

  bf16x8 wx[2][4], wh[2][8];
  #pragma unroll
  for (int m = 0; m < 2; ++m){
    const int g = l16 & 3;
    const int u = 2 * (l16 >> 2) + m;
    const float* rx = Wih0 + (size_t)(g * HH + j0 + u) * EE;
    const float* rh = Whh0 + (size_t)(g * HH + j0 + u) * HH;
    #pragma unroll
    for (int kk = 0; kk < 4; ++kk){
      int k0 = wid * 128 + kk * 32 + kq;
      wx[m][kk] = pack8(*reinterpret_cast<const float4*>(rx + k0),
                        *reinterpret_cast<const float4*>(rx + k0 + 4));
    }
    #pragma unroll
    for (int kk = 0; kk < 8; ++kk){
      int k0 = wid * 256 + kk * 32 + kq;
      wh[m][kk] = pack8(*reinterpret_cast<const float4*>(rh + k0),
                        *reinterpret_cast<const float4*>(rh + k0 + 4));
    }
  }

  float cs[2];
  #pragma unroll
  for (int m = 0; m < 2; ++m)
    cs[m] = c0[(size_t)bown * HH + j0 + 2 * hi + m];

  for (int t = 0; t < TT; ++t){
    f32x4 acc[2][4];
    #pragma unroll
    for (int m = 0; m < 2; ++m)
      #pragma unroll
      for (int nt = 0; nt < 4; ++nt)
        acc[m][nt] = (f32x4){0.f,0.f,0.f,0.f};

    // x-part (emb) before the wait — dependency-free
    {
      const us* xr[4];
      #pragma unroll
      for (int nt = 0; nt < 4; ++nt)
        xr[nt] = emb_bf + (size_t)inputs[t * BB + nt * 16 + l16] * EE;
      #pragma unroll
      for (int kk = 0; kk < 4; ++kk){
        const int kb = wid * 128 + kk * 32 + kq;
        #pragma unroll
        for (int nt = 0; nt < 4; ++nt){
          bf16x8 bf = *reinterpret_cast<const bf16x8*>(xr[nt] + kb);
          acc[0][nt] = MFMA(wx[0][kk], bf, acc[0][nt]);
          acc[1][nt] = MFMA(wx[1][kk], bf, acc[1][nt]);
        }
      }
    }

    // recurrent part — incremental chunk consumption: run chunk kk's MFMAs
    // as soon as its 4 producer blocks have published; h-read of ready chunks
    // overlaps the poll for stragglers.
    {
      const us* hs = (t == 0) ? h0ic : hist0 + (size_t)(t - 1) * BBHH;
      const unsigned* fp = flags0 + wbase + (lane & 31);
      unsigned long long rdy = ~0ULL;
      if (t > 0) rdy = __ballot((int)(LDG(fp) >= (unsigned)t));
      #pragma unroll
      for (int kk = 0; kk < 8; ++kk){
        if (t > 0){
          unsigned long long mk = cmask(kk);
          while ((rdy & mk) != mk){
            __builtin_amdgcn_s_sleep(8);
            rdy = __ballot((int)(LDG(fp) >= (unsigned)t));
          }
        }
        #pragma unroll
        for (int nt = 0; nt < 4; ++nt){
          bf16x8 bf = *reinterpret_cast<const bf16x8*>(hs + cbase + kk * 2048 + nt * 128);
          acc[0][nt] = MFMA(wh[0][kk], bf, acc[0][nt]);
          acc[1][nt] = MFMA(wh[1][kk], bf, acc[1][nt]);
        }
      }
    }

    // cross-wave K reduction (dense 16B/lane -> 0 bank conflicts)
    #pragma unroll
    for (int m = 0; m < 2; ++m)
      #pragma unroll
      for (int nt = 0; nt < 4; ++nt)
        *reinterpret_cast<f32x4*>(&lds[LIDX(m, wid * 4 + nt)]) = acc[m][nt];
    __syncthreads();
    f32x4 s[2];
    #pragma unroll
    for (int m = 0; m < 2; ++m){
      s[m] = (f32x4){0.f,0.f,0.f,0.f};
      #pragma unroll
      for (int w = 0; w < 4; ++w)
        s[m] += *reinterpret_cast<f32x4*>(&lds[LIDX(m, w * 4 + wid)]);
    }

    float hv[2];
    #pragma unroll
    for (int m = 0; m < 2; ++m){
      float gi = sigmoidf_(s[m][0]), gf = sigmoidf_(s[m][1]);
      float gg = tanhf_(s[m][2]),    go = sigmoidf_(s[m][3]);
      cs[m] = gf * cs[m] + gi * gg;
      hv[m] = go * tanhf_(cs[m]);
    }
    // publish: compact layout, block region = 1KB contiguous (8 full lines)
    unsigned w = (unsigned)f2b(hv[0]) | ((unsigned)f2b(hv[1]) << 16);
    __hip_atomic_store(reinterpret_cast<unsigned*>(hist0 + (size_t)t * BBHH + (size_t)(bid_l * BB + bown) * 8 + 2 * hi),
                       w, __ATOMIC_RELAXED, __HIP_MEMORY_SCOPE_AGENT);
    if (t == TT - 1){
      size_t o = (size_t)bown * HH + j0 + 2 * hi;
      *reinterpret_cast<float2*>(hn + o) = make_float2(hv[0], hv[1]);
      *reinterpret_cast<float2*>(cn + o) = make_float2(cs[0], cs[1]);
    }

    publish(flags0, bid_l, (unsigned)(t + 1));
  }
}

__device__ void run_l1(
    int bid_l, int lane, int wid, int l16, int hi, int kq,
    const float* __restrict__ c0,
    const float* __restrict__ Wih1, const float* __restrict__ Whh1,
    const us* __restrict__ h1ic,
    const us* __restrict__ hist0, us* __restrict__ hist1,
    const float* __restrict__ decW, const float* __restrict__ decb,
    float* __restrict__ dec_out, float* __restrict__ hn, float* __restrict__ cn,
    unsigned* __restrict__ flags0, unsigned* __restrict__ flags1, float* lds)
{
  const int j0 = bid_l * 8;
  const int bown = wid * 16 + l16;
  const int cbase = CBASE;
  const int wbase = wid * 32;

  bf16x8 wx[2][8], wh[2][8];
  #pragma unroll
  for (int m = 0; m < 2; ++m){
    const int g = l16 & 3;
    const int u = 2 * (l16 >> 2) + m;
    const float* rx = Wih1 + (size_t)(g * HH + j0 + u) * HH;
    const float* rh = Whh1 + (size_t)(g * HH + j0 + u) * HH;
    #pragma unroll
    for (int kk = 0; kk < 8; ++kk){
      int k0 = wid * 256 + kk * 32 + kq;
      wx[m][kk] = pack8(*reinterpret_cast<const float4*>(rx + k0),
                        *reinterpret_cast<const float4*>(rx + k0 + 4));
      wh[m][kk] = pack8(*reinterpret_cast<const float4*>(rh + k0),
                        *reinterpret_cast<const float4*>(rh + k0 + 4));
    }
  }

  float cs[2];
  #pragma unroll
  for (int m = 0; m < 2; ++m)
    cs[m] = c0[(size_t)BBHH + (size_t)bown * HH + j0 + 2 * hi + m];
  float pooldec = 0.0f;
  const float dwv0 = decW[j0 + 2 * hi], dwv1 = decW[j0 + 2 * hi + 1];

  for (int t = 0; t < TT; ++t){
    f32x4 acc[2][4];
    #pragma unroll
    for (int m = 0; m < 2; ++m)
      #pragma unroll
      for (int nt = 0; nt < 4; ++nt)
        acc[m][nt] = (f32x4){0.f,0.f,0.f,0.f};

    // recurrent part first (own flag usually already satisfied) — incremental
    {
      const us* hs = (t == 0) ? h1ic : hist1 + (size_t)(t - 1) * BBHH;
      const unsigned* fp = flags1 + wbase + (lane & 31);
      unsigned long long rdy = ~0ULL;
      if (t > 0) rdy = __ballot((int)(LDG(fp) >= (unsigned)t));
      #pragma unroll
      for (int kk = 0; kk < 8; ++kk){
        if (t > 0){
          unsigned long long mk = cmask(kk);
          while ((rdy & mk) != mk){
            __builtin_amdgcn_s_sleep(8);
            rdy = __ballot((int)(LDG(fp) >= (unsigned)t));
          }
        }
        #pragma unroll
        for (int nt = 0; nt < 4; ++nt){
          bf16x8 bf = *reinterpret_cast<const bf16x8*>(hs + cbase + kk * 2048 + nt * 128);
          acc[0][nt] = MFMA(wh[0][kk], bf, acc[0][nt]);
          acc[1][nt] = MFMA(wh[1][kk], bf, acc[1][nt]);
        }
      }
    }

    // x-part: h0[t] from layer 0 — incremental on flags0
    {
      const us* xs = hist0 + (size_t)t * BBHH;
      const unsigned* fp = flags0 + wbase + (lane & 31);
      unsigned long long rdy = __ballot((int)(LDG(fp) >= (unsigned)(t + 1)));
      #pragma unroll
      for (int kk = 0; kk < 8; ++kk){
        unsigned long long mk = cmask(kk);
        while ((rdy & mk) != mk){
          __builtin_amdgcn_s_sleep(8);
          rdy = __ballot((int)(LDG(fp) >= (unsigned)(t + 1)));
        }
        #pragma unroll
        for (int nt = 0; nt < 4; ++nt){
          bf16x8 bf = *reinterpret_cast<const bf16x8*>(xs + cbase + kk * 2048 + nt * 128);
          acc[0][nt] = MFMA(wx[0][kk], bf, acc[0][nt]);
          acc[1][nt] = MFMA(wx[1][kk], bf, acc[1][nt]);
        }
      }
    }

    #pragma unroll
    for (int m = 0; m < 2; ++m)
      #pragma unroll
      for (int nt = 0; nt < 4; ++nt)
        *reinterpret_cast<f32x4*>(&lds[LIDX(m, wid * 4 + nt)]) = acc[m][nt];
    __syncthreads();
    f32x4 s[2];
    #pragma unroll
    for (int m = 0; m < 2; ++m){
      s[m] = (f32x4){0.f,0.f,0.f,0.f};
      #pragma unroll
      for (int w = 0; w < 4; ++w)
        s[m] += *reinterpret_cast<f32x4*>(&lds[LIDX(m, w * 4 + wid)]);
    }

    float hv[2];
    #pragma unroll
    for (int m = 0; m < 2; ++m){
      float gi = sigmoidf_(s[m][0]), gf = sigmoidf_(s[m][1]);
      float gg = tanhf_(s[m][2]),    go = sigmoidf_(s[m][3]);
      cs[m] = gf * cs[m] + gi * gg;
      hv[m] = go * tanhf_(cs[m]);
    }
    unsigned w = (unsigned)f2b(hv[0]) | ((unsigned)f2b(hv[1]) << 16);
    __hip_atomic_store(reinterpret_cast<unsigned*>(hist1 + (size_t)t * BBHH + (size_t)(bid_l * BB + bown) * 8 + 2 * hi),
                       w, __ATOMIC_RELAXED, __HIP_MEMORY_SCOPE_AGENT);
    pooldec += hv[0] * dwv0 + hv[1] * dwv1;
    if (t == TT - 1){
      size_t o = (size_t)BBHH + (size_t)bown * HH + j0 + 2 * hi;
      *reinterpret_cast<float2*>(hn + o) = make_float2(hv[0], hv[1]);
      *reinterpret_cast<float2*>(cn + o) = make_float2(cs[0], cs[1]);
    }

    publish(flags1, bid_l, (unsigned)(t + 1));
  }

  pooldec += __shfl_xor(pooldec, 16);
  pooldec += __shfl_xor(pooldec, 32);
  if (hi == 0){
    float contrib = pooldec * (1.0f / (float)TT);
    if (bid_l == 0) contrib += decb[0];
    atomicAdd(&dec_out[bown], contrib);
  }
}

__global__ __launch_bounds__(256, 1) void lstm_persist(
    const int* __restrict__ inputs, const float* __restrict__ c0,
    const us* __restrict__ emb_bf,
    const float* __restrict__ Wih0, const float* __restrict__ Whh0,
    const float* __restrict__ Wih1, const float* __restrict__ Whh1,
    const us* __restrict__ h0ic, const us* __restrict__ h1ic,
    us* __restrict__ hist0, us* __restrict__ hist1,
    const float* __restrict__ decW, const float* __restrict__ decb,
    float* __restrict__ dec_out, float* __restrict__ hn, float* __restrict__ cn,
    unsigned* __restrict__ flags)
{
  __shared__ float lds[2 * 16 * 64 * 4];   // 32 KB
  const int tid  = threadIdx.x;
  const int lane = tid & 63;
  const int wid  = tid >> 6;
  const int l16  = lane & 15;
  const int hi   = lane >> 4;
  const int kq   = hi << 3;
  unsigned* flags0 = flags;
  unsigned* flags1 = flags + 128;

  int bid = blockIdx.x;
  if (bid < BPL){
    run_l0(bid, lane, wid, l16, hi, kq, inputs, c0, emb_bf, Wih0, Whh0,
           h0ic, hist0, hn, cn, flags0, lds);
  } else {
    run_l1(bid - BPL, lane, wid, l16, hi, kq, c0, Wih1, Whh1,
           h1ic, hist0, hist1, decW, decb, dec_out, hn, cn, flags0, flags1, lds);
  }
}

extern "C" void kernel_launch(void* const* d_in, const int* in_sizes, int n_in,
                              void* d_out, int out_size, void* d_ws, size_t ws_size,
                              hipStream_t stream){
  const int*   inputs = (const int*)d_in[0];
  const float* h0     = (const float*)d_in[1];
  const float* c0     = (const float*)d_in[2];
  const float* emb    = (const float*)d_in[3];
  const float* Wih0   = (const float*)d_in[4];
  const float* Whh0   = (const float*)d_in[5];
  const float* Wih1   = (const float*)d_in[6];
  const float* Whh1   = (const float*)d_in[7];
  const float* decW   = (const float*)d_in[8];
  const float* decb   = (const float*)d_in[9];

  char* ws = (char*)d_ws;
  size_t off = 0;
  auto alloc = [&](size_t bytes) -> void* {
    void* p = ws + off;
    off += (bytes + 255) & ~(size_t)255;
    return p;
  };
  us* emb_bf = (us*)alloc((size_t)VV * EE * 2);        // 51.2 MB
  us* hist0  = (us*)alloc((size_t)TT * BBHH * 2);      // 64 MB
  us* hist1  = (us*)alloc((size_t)TT * BBHH * 2);      // 64 MB
  us* h0ic   = (us*)alloc((size_t)BBHH * 2);
  us* h1ic   = (us*)alloc((size_t)BBHH * 2);
  unsigned* flags = (unsigned*)alloc((size_t)256 * 4);

  float* out = (float*)d_out;            // decoded [B]
  float* hn  = out + BB;                 // [2,B,H]
  float* cn  = out + BB + 2 * BBHH;      // [2,B,H]

  hipMemsetAsync(flags, 0, 256 * 4, stream);
  hipMemsetAsync(out, 0, BB * 4, stream);

  cast_f2b<<<2048, 256, 0, stream>>>(emb, emb_bf, (long)VV * EE);
  init_h<<<BBHH / 256, 256, 0, stream>>>(h0, h0ic, h1ic);

  lstm_persist<<<NBLK, 256, 0, stream>>>(inputs, c0, emb_bf,
                                         Wih0, Whh0, Wih1, Whh1,
                                         h0ic, h1ic, hist0, hist1,
                                         decW, decb, out, hn, cn, flags);
}

// Round 16
// 4139.286 us; speedup vs baseline: 1.3828x; 1.3828x over previous
//
#include <hip/hip_runtime.h>

#define TT 512
#define BB 64
#define HH 1024
#define EE 512
#define VV 50000
#define BBHH (BB*HH)
#define BPL 128
#define NBLK 256

typedef __attribute__((ext_vector_type(8))) short bf16x8;
typedef __attribute__((ext_vector_type(4))) float f32x4;
typedef unsigned short us;

#define MFMA(a,b,c) __builtin_amdgcn_mfma_f32_16x16x32_bf16((a),(b),(c),0,0,0)
#define LDG(p) __hip_atomic_load((p), __ATOMIC_RELAXED, __HIP_MEMORY_SCOPE_AGENT)

__device__ inline us f2b(float f){
  unsigned u; __builtin_memcpy(&u, &f, 4);
  return (us)((u + 0x7FFFu + ((u >> 16) & 1u)) >> 16);
}
__device__ inline float sigmoidf_(float x){ return 1.0f / (1.0f + __expf(-x)); }
__device__ inline float tanhf_(float x){ float e = __expf(2.0f * x); return 1.0f - 2.0f / (e + 1.0f); }

__device__ inline bf16x8 pack8(float4 a, float4 b){
  bf16x8 r;
  r[0]=(short)f2b(a.x); r[1]=(short)f2b(a.y); r[2]=(short)f2b(a.z); r[3]=(short)f2b(a.w);
  r[4]=(short)f2b(b.x); r[5]=(short)f2b(b.y); r[6]=(short)f2b(b.z); r[7]=(short)f2b(b.w);
  return r;
}

// ---------------- cast fp32 -> bf16 ----------------
__global__ void cast_f2b(const float* __restrict__ src, us* __restrict__ dst, long n){
  long i = ((long)blockIdx.x * blockDim.x + threadIdx.x) * 4;
  long stride = (long)gridDim.x * blockDim.x * 4;
  for (; i + 3 < n; i += stride){
    float4 v = *reinterpret_cast<const float4*>(src + i);
    ushort4 r; r.x=f2b(v.x); r.y=f2b(v.y); r.z=f2b(v.z); r.w=f2b(v.w);
    *reinterpret_cast<ushort4*>(dst + i) = r;
  }
}

// ---------------- init: h0 fp32 [2,B,H] -> compact [j>>3][b][j&7] bf16 ----------------
__global__ void init_h(const float* __restrict__ h0,
                       us* __restrict__ h0ic, us* __restrict__ h1ic){
  int i = blockIdx.x * blockDim.x + threadIdx.x;   // b*HH + j
  int b = i >> 10, j = i & (HH - 1);
  int d = (((j >> 3) * BB) + b) * 8 + (j & 7);
  h0ic[d] = f2b(h0[i]);
  h1ic[d] = f2b(h0[BBHH + i]);
}

// ---------------- per-wave producer-window wait ----------------
// Wave with K-slice `wid` only consumes kblks [wid*32, wid*32+32) == producer
// blocks in that window. Poll just those 32 flags (one 128B line; 2 lanes per
// flag broadcast). Strictly weaker condition than the all-128 wait.
__device__ __forceinline__ void wait_win(const unsigned* __restrict__ f, int base,
                                         unsigned e, int lane){
  const unsigned* p = f + base + (lane & 31);
  unsigned a = LDG(p);
  while (!__all((int)(a >= e))){
    __builtin_amdgcn_s_sleep(8);
    a = LDG(p);
  }
}

// publish: drain this block's sc1 stores, block-barrier, one flag store
__device__ __forceinline__ void publish(unsigned* __restrict__ f, int bid_l, unsigned e){
  asm volatile("s_waitcnt vmcnt(0)" ::: "memory");
  __syncthreads();
  if (threadIdx.x == 0)
    __hip_atomic_store(f + bid_l, e, __ATOMIC_RELAXED, __HIP_MEMORY_SCOPE_AGENT);
}

// Lane mapping (per m in 0..1): A-row l16 -> (g=l16&3, u=2*(l16>>2)+m);
// D row hi*4+i -> unit j0+2*hi+m, gate i; lane owns batch bown=wid*16+l16.
#define LIDX(m, s) ((((m) * 16 + (s)) * 64 + lane) * 4)

// consumer base offset into compact h: k = wid*256 + kk*32 + kq -> kblk = wid*32+kk*4+hi
#define CBASE ((wid * 32 + hi) * (BB * 8) + l16 * 8)

__device__ void run_l0(
    int bid_l, int lane, int wid, int l16, int hi, int kq,
    const int* __restrict__ inputs, const float* __restrict__ c0,
    const us* __restrict__ emb_bf,
    const float* __restrict__ Wih0, const float* __restrict__ Whh0,
    const us* __restrict__ h0ic,
    us* __restrict__ hist0,
    float* __restrict__ hn, float* __restrict__ cn,
    unsigned* __restrict__ flags0, float* lds)
{
  const int j0 = bid_l * 8;
  const int bown = wid * 16 + l16;
  const int cbase = CBASE;
  const int wbase = wid * 32;

  bf16x8 wx[2][4], wh[2][8];
  #pragma unroll
  for (int m = 0; m < 2; ++m){
    const int g = l16 & 3;
    const int u = 2 * (l16 >> 2) + m;
    const float* rx = Wih0 + (size_t)(g * HH + j0 + u) * EE;
    const float* rh = Whh0 + (size_t)(g * HH + j0 + u) * HH;
    #pragma unroll
    for (int kk = 0; kk < 4; ++kk){
      int k0 = wid * 128 + kk * 32 + kq;
      wx[m][kk] = pack8(*reinterpret_cast<const float4*>(rx + k0),
                        *reinterpret_cast<const float4*>(rx + k0 + 4));
    }
    #pragma unroll
    for (int kk = 0; kk < 8; ++kk){
      int k0 = wid * 256 + kk * 32 + kq;
      wh[m][kk] = pack8(*reinterpret_cast<const float4*>(rh + k0),
                        *reinterpret_cast<const float4*>(rh + k0 + 4));
    }
  }

  float cs[2];
  #pragma unroll
  for (int m = 0; m < 2; ++m)
    cs[m] = c0[(size_t)bown * HH + j0 + 2 * hi + m];

  for (int t = 0; t < TT; ++t){
    f32x4 acc[2][4];
    #pragma unroll
    for (int m = 0; m < 2; ++m)
      #pragma unroll
      for (int nt = 0; nt < 4; ++nt)
        acc[m][nt] = (f32x4){0.f,0.f,0.f,0.f};

    // x-part (emb) before the wait — dependency-free
    {
      const us* xr[4];
      #pragma unroll
      for (int nt = 0; nt < 4; ++nt)
        xr[nt] = emb_bf + (size_t)inputs[t * BB + nt * 16 + l16] * EE;
      #pragma unroll
      for (int kk = 0; kk < 4; ++kk){
        const int kb = wid * 128 + kk * 32 + kq;
        #pragma unroll
        for (int nt = 0; nt < 4; ++nt){
          bf16x8 bf = *reinterpret_cast<const bf16x8*>(xr[nt] + kb);
          acc[0][nt] = MFMA(wx[0][kk], bf, acc[0][nt]);
          acc[1][nt] = MFMA(wx[1][kk], bf, acc[1][nt]);
        }
      }
    }

    if (t > 0) wait_win(flags0, wbase, (unsigned)t, lane);

    // recurrent part (compact layout, full-line coalesced)
    {
      const us* hs = (t == 0) ? h0ic : hist0 + (size_t)(t - 1) * BBHH;
      #pragma unroll
      for (int kk = 0; kk < 8; ++kk){
        #pragma unroll
        for (int nt = 0; nt < 4; ++nt){
          bf16x8 bf = *reinterpret_cast<const bf16x8*>(hs + cbase + kk * 2048 + nt * 128);
          acc[0][nt] = MFMA(wh[0][kk], bf, acc[0][nt]);
          acc[1][nt] = MFMA(wh[1][kk], bf, acc[1][nt]);
        }
      }
    }

    // cross-wave K reduction (dense 16B/lane -> 0 bank conflicts)
    #pragma unroll
    for (int m = 0; m < 2; ++m)
      #pragma unroll
      for (int nt = 0; nt < 4; ++nt)
        *reinterpret_cast<f32x4*>(&lds[LIDX(m, wid * 4 + nt)]) = acc[m][nt];
    __syncthreads();
    f32x4 s[2];
    #pragma unroll
    for (int m = 0; m < 2; ++m){
      s[m] = (f32x4){0.f,0.f,0.f,0.f};
      #pragma unroll
      for (int w = 0; w < 4; ++w)
        s[m] += *reinterpret_cast<f32x4*>(&lds[LIDX(m, w * 4 + wid)]);
    }

    float hv[2];
    #pragma unroll
    for (int m = 0; m < 2; ++m){
      float gi = sigmoidf_(s[m][0]), gf = sigmoidf_(s[m][1]);
      float gg = tanhf_(s[m][2]),    go = sigmoidf_(s[m][3]);
      cs[m] = gf * cs[m] + gi * gg;
      hv[m] = go * tanhf_(cs[m]);
    }
    // publish: compact layout, block region = 1KB contiguous (8 full lines)
    unsigned w = (unsigned)f2b(hv[0]) | ((unsigned)f2b(hv[1]) << 16);
    __hip_atomic_store(reinterpret_cast<unsigned*>(hist0 + (size_t)t * BBHH + (size_t)(bid_l * BB + bown) * 8 + 2 * hi),
                       w, __ATOMIC_RELAXED, __HIP_MEMORY_SCOPE_AGENT);
    if (t == TT - 1){
      size_t o = (size_t)bown * HH + j0 + 2 * hi;
      *reinterpret_cast<float2*>(hn + o) = make_float2(hv[0], hv[1]);
      *reinterpret_cast<float2*>(cn + o) = make_float2(cs[0], cs[1]);
    }

    publish(flags0, bid_l, (unsigned)(t + 1));
  }
}

__device__ void run_l1(
    int bid_l, int lane, int wid, int l16, int hi, int kq,
    const float* __restrict__ c0,
    const float* __restrict__ Wih1, const float* __restrict__ Whh1,
    const us* __restrict__ h1ic,
    const us* __restrict__ hist0, us* __restrict__ hist1,
    const float* __restrict__ decW, const float* __restrict__ decb,
    float* __restrict__ dec_out, float* __restrict__ hn, float* __restrict__ cn,
    unsigned* __restrict__ flags0, unsigned* __restrict__ flags1, float* lds)
{
  const int j0 = bid_l * 8;
  const int bown = wid * 16 + l16;
  const int cbase = CBASE;
  const int wbase = wid * 32;

  bf16x8 wx[2][8], wh[2][8];
  #pragma unroll
  for (int m = 0; m < 2; ++m){
    const int g = l16 & 3;
    const int u = 2 * (l16 >> 2) + m;
    const float* rx = Wih1 + (size_t)(g * HH + j0 + u) * HH;
    const float* rh = Whh1 + (size_t)(g * HH + j0 + u) * HH;
    #pragma unroll
    for (int kk = 0; kk < 8; ++kk){
      int k0 = wid * 256 + kk * 32 + kq;
      wx[m][kk] = pack8(*reinterpret_cast<const float4*>(rx + k0),
                        *reinterpret_cast<const float4*>(rx + k0 + 4));
      wh[m][kk] = pack8(*reinterpret_cast<const float4*>(rh + k0),
                        *reinterpret_cast<const float4*>(rh + k0 + 4));
    }
  }

  float cs[2];
  #pragma unroll
  for (int m = 0; m < 2; ++m)
    cs[m] = c0[(size_t)BBHH + (size_t)bown * HH + j0 + 2 * hi + m];
  float pooldec = 0.0f;
  const float dwv0 = decW[j0 + 2 * hi], dwv1 = decW[j0 + 2 * hi + 1];

  for (int t = 0; t < TT; ++t){
    f32x4 acc[2][4];
    #pragma unroll
    for (int m = 0; m < 2; ++m)
      #pragma unroll
      for (int nt = 0; nt < 4; ++nt)
        acc[m][nt] = (f32x4){0.f,0.f,0.f,0.f};

    // recurrent part first (own flag usually already satisfied) — overlaps L0's tail
    if (t > 0) wait_win(flags1, wbase, (unsigned)t, lane);
    {
      const us* hs = (t == 0) ? h1ic : hist1 + (size_t)(t - 1) * BBHH;
      #pragma unroll
      for (int kk = 0; kk < 8; ++kk){
        #pragma unroll
        for (int nt = 0; nt < 4; ++nt){
          bf16x8 bf = *reinterpret_cast<const bf16x8*>(hs + cbase + kk * 2048 + nt * 128);
          acc[0][nt] = MFMA(wh[0][kk], bf, acc[0][nt]);
          acc[1][nt] = MFMA(wh[1][kk], bf, acc[1][nt]);
        }
      }
    }

    // x-part: h0[t] from layer 0
    wait_win(flags0, wbase, (unsigned)(t + 1), lane);
    {
      const us* xs = hist0 + (size_t)t * BBHH;
      #pragma unroll
      for (int kk = 0; kk < 8; ++kk){
        #pragma unroll
        for (int nt = 0; nt < 4; ++nt){
          bf16x8 bf = *reinterpret_cast<const bf16x8*>(xs + cbase + kk * 2048 + nt * 128);
          acc[0][nt] = MFMA(wx[0][kk], bf, acc[0][nt]);
          acc[1][nt] = MFMA(wx[1][kk], bf, acc[1][nt]);
        }
      }
    }

    #pragma unroll
    for (int m = 0; m < 2; ++m)
      #pragma unroll
      for (int nt = 0; nt < 4; ++nt)
        *reinterpret_cast<f32x4*>(&lds[LIDX(m, wid * 4 + nt)]) = acc[m][nt];
    __syncthreads();
    f32x4 s[2];
    #pragma unroll
    for (int m = 0; m < 2; ++m){
      s[m] = (f32x4){0.f,0.f,0.f,0.f};
      #pragma unroll
      for (int w = 0; w < 4; ++w)
        s[m] += *reinterpret_cast<f32x4*>(&lds[LIDX(m, w * 4 + wid)]);
    }

    float hv[2];
    #pragma unroll
    for (int m = 0; m < 2; ++m){
      float gi = sigmoidf_(s[m][0]), gf = sigmoidf_(s[m][1]);
      float gg = tanhf_(s[m][2]),    go = sigmoidf_(s[m][3]);
      cs[m] = gf * cs[m] + gi * gg;
      hv[m] = go * tanhf_(cs[m]);
    }
    unsigned w = (unsigned)f2b(hv[0]) | ((unsigned)f2b(hv[1]) << 16);
    __hip_atomic_store(reinterpret_cast<unsigned*>(hist1 + (size_t)t * BBHH + (size_t)(bid_l * BB + bown) * 8 + 2 * hi),
                       w, __ATOMIC_RELAXED, __HIP_MEMORY_SCOPE_AGENT);
    pooldec += hv[0] * dwv0 + hv[1] * dwv1;
    if (t == TT - 1){
      size_t o = (size_t)BBHH + (size_t)bown * HH + j0 + 2 * hi;
      *reinterpret_cast<float2*>(hn + o) = make_float2(hv[0], hv[1]);
      *reinterpret_cast<float2*>(cn + o) = make_float2(cs[0], cs[1]);
    }

    publish(flags1, bid_l, (unsigned)(t + 1));
  }

  pooldec += __shfl_xor(pooldec, 16);
  pooldec += __shfl_xor(pooldec, 32);
  if (hi == 0){
    float contrib = pooldec * (1.0f / (float)TT);
    if (bid_l == 0) contrib += decb[0];
    atomicAdd(&dec_out[bown], contrib);
  }
}

__global__ __launch_bounds__(256, 1) void lstm_persist(
    const int* __restrict__ inputs, const float* __restrict__ c0,
    const us* __restrict__ emb_bf,
    const float* __restrict__ Wih0, const float* __restrict__ Whh0,
    const float* __restrict__ Wih1, const float* __restrict__ Whh1,
    const us* __restrict__ h0ic, const us* __restrict__ h1ic,
    us* __restrict__ hist0, us* __restrict__ hist1,
    const float* __restrict__ decW, const float* __restrict__ decb,
    float* __restrict__ dec_out, float* __restrict__ hn, float* __restrict__ cn,
    unsigned* __restrict__ flags)
{
  __shared__ float lds[2 * 16 * 64 * 4];   // 32 KB
  const int tid  = threadIdx.x;
  const int lane = tid & 63;
  const int wid  = tid >> 6;
  const int l16  = lane & 15;
  const int hi   = lane >> 4;
  const int kq   = hi << 3;
  unsigned* flags0 = flags;
  unsigned* flags1 = flags + 128;

  int bid = blockIdx.x;
  if (bid < BPL){
    run_l0(bid, lane, wid, l16, hi, kq, inputs, c0, emb_bf, Wih0, Whh0,
           h0ic, hist0, hn, cn, flags0, lds);
  } else {
    run_l1(bid - BPL, lane, wid, l16, hi, kq, c0, Wih1, Whh1,
           h1ic, hist0, hist1, decW, decb, dec_out, hn, cn, flags0, flags1, lds);
  }
}

extern "C" void kernel_launch(void* const* d_in, const int* in_sizes, int n_in,
                              void* d_out, int out_size, void* d_ws, size_t ws_size,
                              hipStream_t stream){
  const int*   inputs = (const int*)d_in[0];
  const float* h0     = (const float*)d_in[1];
  const float* c0     = (const float*)d_in[2];
  const float* emb    = (const float*)d_in[3];
  const float* Wih0   = (const float*)d_in[4];
  const float* Whh0   = (const float*)d_in[5];
  const float* Wih1   = (const float*)d_in[6];
  const float* Whh1   = (const float*)d_in[7];
  const float* decW   = (const float*)d_in[8];
  const float* decb   = (const float*)d_in[9];

  char* ws = (char*)d_ws;
  size_t off = 0;
  auto alloc = [&](size_t bytes) -> void* {
    void* p = ws + off;
    off += (bytes + 255) & ~(size_t)255;
    return p;
  };
  us* emb_bf = (us*)alloc((size_t)VV * EE * 2);        // 51.2 MB
  us* hist0  = (us*)alloc((size_t)TT * BBHH * 2);      // 64 MB
  us* hist1  = (us*)alloc((size_t)TT * BBHH * 2);      // 64 MB
  us* h0ic   = (us*)alloc((size_t)BBHH * 2);
  us* h1ic   = (us*)alloc((size_t)BBHH * 2);
  unsigned* flags = (unsigned*)alloc((size_t)256 * 4);

  float* out = (float*)d_out;            // decoded [B]
  float* hn  = out + BB;                 // [2,B,H]
  float* cn  = out + BB + 2 * BBHH;      // [2,B,H]

  hipMemsetAsync(flags, 0, 256 * 4, stream);
  hipMemsetAsync(out, 0, BB * 4, stream);

  cast_f2b<<<2048, 256, 0, stream>>>(emb, emb_bf, (long)VV * EE);
  init_h<<<BBHH / 256, 256, 0, stream>>>(h0, h0ic, h1ic);

  lstm_persist<<<NBLK, 256, 0, stream>>>(inputs, c0, emb_bf,
                                         Wih0, Whh0, Wih1, Whh1,
                                         h0ic, h1ic, hist0, hist1,
                                         decW, decb, out, hn, cn, flags);
}